// Round 1
// baseline (472.062 us; speedup 1.0000x reference)
//
#include <hip/hip_runtime.h>
#include <hip/hip_bf16.h>

#define SEQ 4096
#define BSZ 2
#define NH 8
#define HD 64
#define DMODEL 512

typedef __bf16 bf16_t;
typedef __bf16 bf16x8 __attribute__((ext_vector_type(8)));
typedef float f32x4 __attribute__((ext_vector_type(4)));

__device__ __forceinline__ f32x4 mfma16(bf16x8 a, bf16x8 b, f32x4 c) {
    return __builtin_amdgcn_mfma_f32_16x16x32_bf16(a, b, c, 0, 0, 0);
}

__device__ __forceinline__ bf16x8 ld8(const bf16_t* p) {
    return *reinterpret_cast<const bf16x8*>(p);
}

// ---------------- cast fp32 -> bf16 ----------------
__global__ void cast_kernel(const float* __restrict__ src, bf16_t* __restrict__ dst, int n) {
    int i = blockIdx.x * blockDim.x + threadIdx.x;
    if (i < n) dst[i] = (bf16_t)src[i];
}

// ---------------- GEMM1: X(8192x512) @ W^T(1536x512) -> scatter Q,K,V [b,h,s,d] ----------------
__global__ __launch_bounds__(256) void gemm_qkv(const bf16_t* __restrict__ A,
                                                const bf16_t* __restrict__ W,
                                                bf16_t* __restrict__ Qb,
                                                bf16_t* __restrict__ Kb,
                                                bf16_t* __restrict__ Vb) {
    const int K = 512;
    int lane = threadIdx.x & 63;
    int wid = threadIdx.x >> 6;
    int wm = wid & 1, wn = wid >> 1;
    int m0 = blockIdx.x * 128 + wm * 64;
    int n0 = blockIdx.y * 128 + wn * 64;
    int c = lane & 15, quad = lane >> 4;

    f32x4 acc[4][4];
#pragma unroll
    for (int i = 0; i < 4; i++)
#pragma unroll
        for (int j = 0; j < 4; j++) acc[i][j] = f32x4{0.f, 0.f, 0.f, 0.f};

    const bf16_t* Ap = A + (size_t)(m0 + c) * K + quad * 8;
    const bf16_t* Bp = W + (size_t)(n0 + c) * K + quad * 8;

#pragma unroll 2
    for (int k0 = 0; k0 < K; k0 += 32) {
        bf16x8 a[4], b[4];
#pragma unroll
        for (int t = 0; t < 4; t++) a[t] = ld8(Ap + (size_t)t * 16 * K + k0);
#pragma unroll
        for (int t = 0; t < 4; t++) b[t] = ld8(Bp + (size_t)t * 16 * K + k0);
#pragma unroll
        for (int i = 0; i < 4; i++)
#pragma unroll
            for (int j = 0; j < 4; j++) acc[i][j] = mfma16(a[i], b[j], acc[i][j]);
    }

    // scatter epilogue: col -> (which, h, d); row -> (b, s)
#pragma unroll
    for (int i = 0; i < 4; i++) {
        int mbase = m0 + i * 16 + quad * 4;
#pragma unroll
        for (int j = 0; j < 4; j++) {
            int col = n0 + j * 16 + c;
            int which = col >> 9;
            int h = (col >> 6) & 7;
            int d = col & 63;
            bf16_t* dst = (which == 0) ? Qb : ((which == 1) ? Kb : Vb);
#pragma unroll
            for (int r = 0; r < 4; r++) {
                int m = mbase + r;
                int b_ = m >> 12;
                int s = m & 4095;
                dst[((size_t)(b_ * NH + h) * SEQ + s) * HD + d] = (bf16_t)acc[i][j][r];
            }
        }
    }
}

// ---------------- RoPE in-place on [b,h,s,64] bf16; optional scale fold ----------------
__global__ void rope_kernel(bf16_t* __restrict__ X, const int* __restrict__ Vp, float outscale) {
    int n = BSZ * NH * SEQ * 32;
    int i = blockIdx.x * blockDim.x + threadIdx.x;
    if (i >= n) return;
    int pi = i & 31;       // pair index within head dim
    int r = i >> 5;        // row over [b,h,s]
    int s = r & (SEQ - 1);
    int V = Vp[0];
    int f, pos;
    if (pi < 16) { f = pi;      pos = s / V; }
    else         { f = pi - 16; pos = s % V; }
    // 10000^(-f/16) = 2^(-f * log2(10000)/16)
    float inv = exp2f((float)f * -0.8304820237218407f);
    float ang = (float)pos * inv;
    float cs = cosf(ang), sn = sinf(ang);
    size_t base = (size_t)r * HD + pi * 2;
    float xe = (float)X[base];
    float xo = (float)X[base + 1];
    X[base]     = (bf16_t)((xe * cs - xo * sn) * outscale);
    X[base + 1] = (bf16_t)((xe * sn + xo * cs) * outscale);
}

// ---------------- Flash attention: Q,K,V [bh, s, 64] bf16 -> Y [b, s, h*64+d] bf16 ----------------
__global__ __launch_bounds__(256) void flash_attn(const bf16_t* __restrict__ Q,
                                                  const bf16_t* __restrict__ K,
                                                  const bf16_t* __restrict__ V,
                                                  bf16_t* __restrict__ Y) {
    __shared__ alignas(16) bf16_t Pbuf[4][32][72];
    __shared__ alignas(16) bf16_t Vt[64][72];

    int lane = threadIdx.x & 63;
    int wid = threadIdx.x >> 6;
    int c = lane & 15, quad = lane >> 4;
    int bh = blockIdx.y;            // 0..15
    int q0 = blockIdx.x * 128;      // q tile base

    size_t base = (size_t)bh * SEQ * HD;
    const bf16_t* Qp = Q + base;
    const bf16_t* Kp = K + base;
    const bf16_t* Vp = V + base;

    int qrow = q0 + wid * 32;
    bf16x8 qf[2][2];
#pragma unroll
    for (int mt = 0; mt < 2; mt++)
#pragma unroll
        for (int ks = 0; ks < 2; ks++)
            qf[mt][ks] = ld8(Qp + (size_t)(qrow + mt * 16 + c) * HD + ks * 32 + quad * 8);

    f32x4 accO[2][4];
    float mrun[2][4], lrun[2][4];
#pragma unroll
    for (int i = 0; i < 2; i++)
#pragma unroll
        for (int j = 0; j < 4; j++) {
            accO[i][j] = f32x4{0.f, 0.f, 0.f, 0.f};
            mrun[i][j] = -1e30f;
            lrun[i][j] = 0.f;
        }

    int vr = threadIdx.x >> 2;          // 0..63 (kv row in tile)
    int vc0 = (threadIdx.x & 3) * 16;   // 0,16,32,48 (d base)

    for (int kt = 0; kt < SEQ / 64; kt++) {
        int kv0 = kt * 64;
        __syncthreads();  // protect Vt/Pbuf from previous iteration's readers

        // stage V tile transposed: Vt[d][kv]
        {
            bf16x8 v0 = ld8(Vp + (size_t)(kv0 + vr) * HD + vc0);
            bf16x8 v1 = ld8(Vp + (size_t)(kv0 + vr) * HD + vc0 + 8);
#pragma unroll
            for (int j = 0; j < 8; j++) Vt[vc0 + j][vr] = v0[j];
#pragma unroll
            for (int j = 0; j < 8; j++) Vt[vc0 + 8 + j][vr] = v1[j];
        }

        // S = Q K^T  (scale already folded into Q)
        bf16x8 kf[4][2];
#pragma unroll
        for (int nt = 0; nt < 4; nt++)
#pragma unroll
            for (int ks = 0; ks < 2; ks++)
                kf[nt][ks] = ld8(Kp + (size_t)(kv0 + nt * 16 + c) * HD + ks * 32 + quad * 8);

        f32x4 sfrag[2][4];
#pragma unroll
        for (int mt = 0; mt < 2; mt++)
#pragma unroll
            for (int nt = 0; nt < 4; nt++) {
                f32x4 a = f32x4{0.f, 0.f, 0.f, 0.f};
                a = mfma16(qf[mt][0], kf[nt][0], a);
                a = mfma16(qf[mt][1], kf[nt][1], a);
                sfrag[mt][nt] = a;
            }

        // online softmax per row (row = mt*16 + quad*4 + j, cols across 16 lanes x 4 nt)
#pragma unroll
        for (int mt = 0; mt < 2; mt++)
#pragma unroll
            for (int j = 0; j < 4; j++) {
                float mx = fmaxf(fmaxf(sfrag[mt][0][j], sfrag[mt][1][j]),
                                 fmaxf(sfrag[mt][2][j], sfrag[mt][3][j]));
#pragma unroll
                for (int sh = 1; sh < 16; sh <<= 1) mx = fmaxf(mx, __shfl_xor(mx, sh, 64));
                float mnew = fmaxf(mrun[mt][j], mx);
                float al = __expf(mrun[mt][j] - mnew);
                float rs = 0.f;
#pragma unroll
                for (int nt = 0; nt < 4; nt++) {
                    float p = __expf(sfrag[mt][nt][j] - mnew);
                    sfrag[mt][nt][j] = p;
                    rs += p;
                }
#pragma unroll
                for (int sh = 1; sh < 16; sh <<= 1) rs += __shfl_xor(rs, sh, 64);
                lrun[mt][j] = lrun[mt][j] * al + rs;
                mrun[mt][j] = mnew;
#pragma unroll
                for (int nt = 0; nt < 4; nt++) accO[mt][nt][j] *= al;
            }

        // write P to LDS (C-layout -> A-layout transform)
#pragma unroll
        for (int mt = 0; mt < 2; mt++)
#pragma unroll
            for (int nt = 0; nt < 4; nt++)
#pragma unroll
                for (int j = 0; j < 4; j++)
                    Pbuf[wid][mt * 16 + quad * 4 + j][nt * 16 + c] = (bf16_t)sfrag[mt][nt][j];

        __syncthreads();  // Vt staged by all + P visible

        // O += P @ Vtile
#pragma unroll
        for (int ks = 0; ks < 2; ks++) {
            bf16x8 pv[2], vv[4];
#pragma unroll
            for (int mt = 0; mt < 2; mt++) pv[mt] = ld8(&Pbuf[wid][mt * 16 + c][ks * 32 + quad * 8]);
#pragma unroll
            for (int nt = 0; nt < 4; nt++) vv[nt] = ld8(&Vt[nt * 16 + c][ks * 32 + quad * 8]);
#pragma unroll
            for (int mt = 0; mt < 2; mt++)
#pragma unroll
                for (int nt = 0; nt < 4; nt++)
                    accO[mt][nt] = mfma16(pv[mt], vv[nt], accO[mt][nt]);
        }
    }

    // epilogue: Y[b][s][h*64+d] = O / l
    int b_ = bh >> 3, h = bh & 7;
#pragma unroll
    for (int mt = 0; mt < 2; mt++)
#pragma unroll
        for (int j = 0; j < 4; j++) {
            int srow = qrow + mt * 16 + quad * 4 + j;
            float inv_l = 1.0f / lrun[mt][j];
#pragma unroll
            for (int nt = 0; nt < 4; nt++) {
                int d = nt * 16 + c;
                Y[(size_t)(b_ * SEQ + srow) * DMODEL + h * HD + d] = (bf16_t)(accO[mt][nt][j] * inv_l);
            }
        }
}

// ---------------- GEMM2: Y(8192x512) @ Wo^T(512x512) -> out fp32 ----------------
__global__ __launch_bounds__(256) void gemm_out(const bf16_t* __restrict__ A,
                                                const bf16_t* __restrict__ W,
                                                float* __restrict__ out) {
    const int K = 512;
    int lane = threadIdx.x & 63;
    int wid = threadIdx.x >> 6;
    int wm = wid & 1, wn = wid >> 1;
    int m0 = blockIdx.x * 128 + wm * 64;
    int n0 = blockIdx.y * 128 + wn * 64;
    int c = lane & 15, quad = lane >> 4;

    f32x4 acc[4][4];
#pragma unroll
    for (int i = 0; i < 4; i++)
#pragma unroll
        for (int j = 0; j < 4; j++) acc[i][j] = f32x4{0.f, 0.f, 0.f, 0.f};

    const bf16_t* Ap = A + (size_t)(m0 + c) * K + quad * 8;
    const bf16_t* Bp = W + (size_t)(n0 + c) * K + quad * 8;

#pragma unroll 2
    for (int k0 = 0; k0 < K; k0 += 32) {
        bf16x8 a[4], b[4];
#pragma unroll
        for (int t = 0; t < 4; t++) a[t] = ld8(Ap + (size_t)t * 16 * K + k0);
#pragma unroll
        for (int t = 0; t < 4; t++) b[t] = ld8(Bp + (size_t)t * 16 * K + k0);
#pragma unroll
        for (int i = 0; i < 4; i++)
#pragma unroll
            for (int j = 0; j < 4; j++) acc[i][j] = mfma16(a[i], b[j], acc[i][j]);
    }

#pragma unroll
    for (int i = 0; i < 4; i++) {
        int mbase = m0 + i * 16 + quad * 4;
#pragma unroll
        for (int j = 0; j < 4; j++) {
            int col = n0 + j * 16 + c;
#pragma unroll
            for (int r = 0; r < 4; r++) {
                out[(size_t)(mbase + r) * DMODEL + col] = acc[i][j][r];
            }
        }
    }
}

extern "C" void kernel_launch(void* const* d_in, const int* in_sizes, int n_in,
                              void* d_out, int out_size, void* d_ws, size_t ws_size,
                              hipStream_t stream) {
    (void)in_sizes; (void)n_in; (void)out_size; (void)ws_size;
    const float* x  = (const float*)d_in[0];
    const float* Wq = (const float*)d_in[1];
    const float* Wk = (const float*)d_in[2];
    const float* Wv = (const float*)d_in[3];
    const float* Wo = (const float*)d_in[4];
    const int*   Vp = (const int*)d_in[6];
    float* out = (float*)d_out;

    bf16_t* ws  = (bf16_t*)d_ws;
    bf16_t* Xb  = ws;                    // 8192*512      = 4,194,304
    bf16_t* Wc  = Xb  + 4194304;         // 3*512*512     =   786,432
    bf16_t* Wob = Wc  + 786432;          // 512*512       =   262,144
    bf16_t* Qb  = Wob + 262144;          // 4,194,304
    bf16_t* Kb  = Qb  + 4194304;         // 4,194,304
    bf16_t* Vb  = Kb  + 4194304;         // 4,194,304
    bf16_t* Yb  = Vb  + 4194304;         // 4,194,304  (total ~44 MB)

    cast_kernel<<<16384, 256, 0, stream>>>(x, Xb, 4194304);
    cast_kernel<<<1024, 256, 0, stream>>>(Wq, Wc, 262144);
    cast_kernel<<<1024, 256, 0, stream>>>(Wk, Wc + 262144, 262144);
    cast_kernel<<<1024, 256, 0, stream>>>(Wv, Wc + 524288, 262144);
    cast_kernel<<<1024, 256, 0, stream>>>(Wo, Wob, 262144);

    gemm_qkv<<<dim3(64, 12), 256, 0, stream>>>(Xb, Wc, Qb, Kb, Vb);

    rope_kernel<<<8192, 256, 0, stream>>>(Qb, Vp, 0.125f);  // fold hd^-0.5 into Q
    rope_kernel<<<8192, 256, 0, stream>>>(Kb, Vp, 1.0f);

    flash_attn<<<dim3(32, 16), 256, 0, stream>>>(Qb, Kb, Vb, Yb);

    gemm_out<<<dim3(64, 4), 256, 0, stream>>>(Yb, Wob, out);
}